// Round 4
// baseline (615.063 us; speedup 1.0000x reference)
//
#include <hip/hip_runtime.h>

#define TT 1024
#define BB 2048
#define K1 8
#define L2E2 2.8853900817779268f  // 2*log2(e)

// DPP helpers ----------------------------------------------------------------
template <int CTRL>
__device__ __forceinline__ float dpp_add(float x) {
  int y = __builtin_amdgcn_update_dpp(0, __float_as_int(x), CTRL, 0xF, 0xF, true);
  return x + __int_as_float(y);
}
// Two interleaved 16-lane sums (hides DPP-after-VALU hazard gaps).
__device__ __forceinline__ void sum16x2(float& a, float& b) {
  a = dpp_add<0xB1>(a);  b = dpp_add<0xB1>(b);   // quad_perm xor1
  a = dpp_add<0x4E>(a);  b = dpp_add<0x4E>(b);   // quad_perm xor2
  a = dpp_add<0x141>(a); b = dpp_add<0x141>(b);  // row_half_mirror
  a = dpp_add<0x140>(a); b = dpp_add<0x140>(b);  // row_mirror
}
// ROW_BCAST15: row r gets last lane of row r-1 (row0 -> 0). Forward-only.
__device__ __forceinline__ float bcast15(float x) {
  return __int_as_float(
      __builtin_amdgcn_update_dpp(0, __float_as_int(x), 0x142, 0xF, 0xF, true));
}

// ---------------------------------------------------------------------------
// Phase 1: sequential RK4 scan. 2 elements/wave, 32 lanes/element:
//   even 16-lane row: NN1, state A            (eval2 is a finite dummy)
//   odd  16-lane row: NN2(B) + NN3(C), states S1=B, S2=C
// Per stage: 2 eval streams, per-lane combos qb,qc, two sum16s, ONE forward
// bcast15 (P1 -> odd row). No DS ops anywhere in the chain.
//   even: K1 = fma(-.1,A,ut)  - Qb(=P1)            K2 = junk-but-finite
//   odd : K1 = fma(-.1,B,cbC) + Qb(=-3P2+P3) + (5/3)*P1m
//         K2 = fma(-.1,C,ccC) + Qc(=P2-P3)
// 1024 waves = 1 wave on every SIMD. u prefetched per 8-step chunk; outputs
// staged in regs, stores batched per chunk (no memory in the serial chain).
__global__ __launch_bounds__(128) void phase1_kernel(
    const float* __restrict__ useq, const float* __restrict__ x0,
    const float* __restrict__ r1W0, const float* __restrict__ r1b0,
    const float* __restrict__ r1W1, const float* __restrict__ r1b1,
    const float* __restrict__ r2W0, const float* __restrict__ r2b0,
    const float* __restrict__ r2W1, const float* __restrict__ r2b1,
    const float* __restrict__ r3W0, const float* __restrict__ r3b0,
    const float* __restrict__ r3W1, const float* __restrict__ r3b1,
    float* __restrict__ out) {
  const int lane = threadIdx.x & 63;
  const int j = lane & 15;
  const bool odd = (lane >> 4) & 1;
  const int e = blockIdx.x * 4 + (threadIdx.x >> 5);

  // Per-lane folded weights.
  float w0e1, b0e1, w0e2, b0e2, X, Y, Z;
  if (odd) {
    w0e1 = r2W0[j] * L2E2; b0e1 = r2b0[j] * L2E2;
    w0e2 = r3W0[j] * L2E2; b0e2 = r3b0[j] * L2E2;
    X = 6.0f * r2W1[j];    // -3*wn2
    Y = -2.0f * r3W1[j];   // wn3
    Z = -2.0f * r2W1[j];   // wn2
  } else {
    w0e1 = r1W0[j] * L2E2; b0e1 = r1b0[j] * L2E2;
    w0e2 = 0.0f; b0e2 = 0.0f;  // exp2(0)=1 -> rcp(2)=0.5, always finite
    X = -2.0f * r1W1[j];   // wn1
    Y = 0.0f; Z = 0.0f;
  }

  // C_i = b1_i + sum_j W1_i[j]  (uniform, init-only).
  float C1 = r1b1[0], C2 = r2b1[0], C3 = r3b1[0];
  for (int q = 0; q < 16; ++q) {
    C1 += r1W1[q]; C2 += r2W1[q]; C3 += r3W1[q];
  }
  const float caC = 0.2f - C1;
  const float cbC = -1.0f / 6.0f + (5.0f / 3.0f) * C1 - 3.0f * C2 + C3;
  const float ccC = -1.0f / 6.0f + C2 - C3;

  const float sQ = odd ? 1.0f : -1.0f;
  const float mu = odd ? (5.0f / 3.0f) : 0.0f;  // masks garbage P1m on evens
  const float sC = odd ? 1.0f : 0.0f;
  const float cst2 = ccC;  // even rows: harmless stable dummy dynamics

  float S1 = x0[e * 15 + (odd ? 1 : 0)];
  float S2 = x0[e * 15 + (odd ? 2 : 0)];

  const float* up = useq + e * TT;
  float* op = out + (size_t)e * TT * 4;

#define STAGE(SS1, SS2, KK1, KK2)                                        \
  {                                                                      \
    float rv1 = __builtin_amdgcn_rcpf(                                   \
        __builtin_amdgcn_exp2f(fmaf(w0e1, (SS1), b0e1)) + 1.0f);         \
    float rv2 = __builtin_amdgcn_rcpf(                                   \
        __builtin_amdgcn_exp2f(fmaf(w0e2, (SS2), b0e2)) + 1.0f);         \
    float m3 = Y * rv2;                                                  \
    float qb = fmaf(X, rv1, m3);                                         \
    float qc = fmaf(Z, rv1, -m3);                                        \
    sum16x2(qb, qc);                                                     \
    float p1m = bcast15(qb);                                             \
    KK1 = fmaf(sQ, qb, fmaf(-0.1f, (SS1), cst1));                        \
    KK1 = fmaf(mu, p1m, KK1);                                            \
    KK2 = fmaf(sC, qc, fmaf(-0.1f, (SS2), cst2));                        \
  }

#define STEP(UQ, SA_, SB_)                                               \
  {                                                                      \
    const float utv = fmaf(0.1f, (UQ), caC);                             \
    const float cst1 = odd ? cbC : utv;                                  \
    SA_ = S1; SB_ = S2;                                                  \
    float k1a, k1b, k2a, k2b, k3a, k3b, k4a, k4b;                        \
    STAGE(S1, S2, k1a, k1b)                                              \
    float t1 = fmaf(0.5f, k1a, S1), t2 = fmaf(0.5f, k1b, S2);            \
    STAGE(t1, t2, k2a, k2b)                                              \
    t1 = fmaf(0.5f, k2a, S1); t2 = fmaf(0.5f, k2b, S2);                  \
    STAGE(t1, t2, k3a, k3b)                                              \
    t1 = S1 + k3a; t2 = S2 + k3b;                                        \
    STAGE(t1, t2, k4a, k4b)                                              \
    S1 = fmaf(1.0f / 6.0f, fmaf(2.0f, k2a + k3a, k1a) + k4a, S1);        \
    S2 = fmaf(1.0f / 6.0f, fmaf(2.0f, k2b + k3b, k1b) + k4b, S2);        \
  }

  float uc0, uc1, uc2, uc3, uc4, uc5, uc6, uc7;
  {
    float4 a = *(const float4*)(up);
    float4 b = *(const float4*)(up + 4);
    uc0 = a.x; uc1 = a.y; uc2 = a.z; uc3 = a.w;
    uc4 = b.x; uc5 = b.y; uc6 = b.z; uc7 = b.w;
  }

  for (int t0 = 0; t0 < TT; t0 += K1) {
    const int tn = (t0 + K1 <= TT - K1) ? (t0 + K1) : (TT - K1);
    const float4 na = *(const float4*)(up + tn);
    const float4 nb = *(const float4*)(up + tn + 4);

    float sA0, sA1, sA2, sA3, sA4, sA5, sA6, sA7;
    float sB0, sB1, sB2, sB3, sB4, sB5, sB6, sB7;
    STEP(uc0, sA0, sB0)
    STEP(uc1, sA1, sB1)
    STEP(uc2, sA2, sB2)
    STEP(uc3, sA3, sB3)
    STEP(uc4, sA4, sB4)
    STEP(uc5, sA5, sB5)
    STEP(uc6, sA6, sB6)
    STEP(uc7, sA7, sB7)

    // Batched stores: even j0 lane -> A at +0; odd j0 lane -> B at +1, C at +2.
    if (j == 0) {
      float* p = op + t0 * 4;
      if (!odd) {
        p[0] = sA0;  p[4] = sA1;  p[8] = sA2;  p[12] = sA3;
        p[16] = sA4; p[20] = sA5; p[24] = sA6; p[28] = sA7;
      } else {
        p[1] = sA0;  p[5] = sA1;  p[9] = sA2;  p[13] = sA3;
        p[17] = sA4; p[21] = sA5; p[25] = sA6; p[29] = sA7;
        p[2] = sB0;  p[6] = sB1;  p[10] = sB2; p[14] = sB3;
        p[18] = sB4; p[22] = sB5; p[26] = sB6; p[30] = sB7;
      }
    }

    uc0 = na.x; uc1 = na.y; uc2 = na.z; uc3 = na.w;
    uc4 = nb.x; uc5 = nb.y; uc6 = nb.z; uc7 = nb.w;
  }
#undef STEP
#undef STAGE
}

// ---------------------------------------------------------------------------
// Phase 2: out[b,t,3] = estC(z_t). One lane per sample; folded weights staged
// in LDS, read as same-address float4 (ds_read_b128 broadcast, conflict-free).
__global__ __launch_bounds__(256) void phase2_kernel(
    const float* __restrict__ useq, const float* __restrict__ x0,
    const float* __restrict__ W0, const float* __restrict__ b0,
    const float* __restrict__ W1, const float* __restrict__ b1p,
    float* __restrict__ out) {
  __shared__ float4 wrow[32][4];  // {w0..3},{w4..7},{w8..11},{b0s,w1n,-,-}
  for (int idx = threadIdx.x; idx < 512; idx += 256) {
    const int h = idx >> 4, r = idx & 15;
    float v = 0.0f;
    if (r < 12) v = W0[r * 32 + h] * L2E2;
    else if (r == 12) v = b0[h] * L2E2;
    else if (r == 13) v = -2.0f * W1[h];
    ((float*)&wrow[h][0])[r] = v;
  }
  __syncthreads();

  float base = b1p[0];
#pragma unroll
  for (int h = 0; h < 32; ++h) base += W1[h];  // uniform s_loads, cached

  const int g = blockIdx.x * 256 + threadIdx.x;  // sample = b*1024 + t
  const int b = g >> 10;
  const int t = g & 1023;

  float z[12];
  if (t >= 4) {
    const float* px = out + (size_t)g * 4;
#pragma unroll
    for (int i = 0; i < 4; ++i) {
      z[2 * i] = px[(i - 4) * 4 + 0];
      z[2 * i + 1] = px[(i - 4) * 4 + 1];
    }
    const float* pu = useq + g;
#pragma unroll
    for (int i = 0; i < 4; ++i) z[8 + i] = pu[i - 4];
  } else {
    const float* xrow = x0 + b * 15;
#pragma unroll
    for (int i = 0; i < 4; ++i) {
      const int s4 = t - 4 + i;
      const float* py = (s4 >= 0) ? (out + ((size_t)(b << 10) + s4) * 4)
                                  : (xrow + 3 + 2 * (i + t));
      z[2 * i] = py[0];
      z[2 * i + 1] = py[1];
      const float* pu = (s4 >= 0) ? (useq + (b << 10) + s4)
                                  : (xrow + 11 + i + t);
      z[8 + i] = pu[0];
    }
  }

  float ov = base;
#pragma unroll
  for (int h = 0; h < 32; ++h) {
    const float4 wa = wrow[h][0];
    const float4 wb = wrow[h][1];
    const float4 wc = wrow[h][2];
    const float4 wd = wrow[h][3];
    float a = wd.x;
    a = fmaf(z[0], wa.x, a);  a = fmaf(z[1], wa.y, a);
    a = fmaf(z[2], wa.z, a);  a = fmaf(z[3], wa.w, a);
    a = fmaf(z[4], wb.x, a);  a = fmaf(z[5], wb.y, a);
    a = fmaf(z[6], wb.z, a);  a = fmaf(z[7], wb.w, a);
    a = fmaf(z[8], wc.x, a);  a = fmaf(z[9], wc.y, a);
    a = fmaf(z[10], wc.z, a); a = fmaf(z[11], wc.w, a);
    const float r = __builtin_amdgcn_rcpf(__builtin_amdgcn_exp2f(a) + 1.0f);
    ov = fmaf(wd.y, r, ov);
  }
  out[(size_t)g * 4 + 3] = ov;
}

// ---------------------------------------------------------------------------
extern "C" void kernel_launch(void* const* d_in, const int* in_sizes, int n_in,
                              void* d_out, int out_size, void* d_ws,
                              size_t ws_size, hipStream_t stream) {
  const float* useq = (const float*)d_in[0];
  const float* x0 = (const float*)d_in[1];
  float* out = (float*)d_out;

  phase1_kernel<<<BB / 4, 128, 0, stream>>>(
      useq, x0,
      (const float*)d_in[2], (const float*)d_in[3], (const float*)d_in[4],
      (const float*)d_in[5], (const float*)d_in[6], (const float*)d_in[7],
      (const float*)d_in[8], (const float*)d_in[9], (const float*)d_in[10],
      (const float*)d_in[11], (const float*)d_in[12], (const float*)d_in[13],
      out);

  phase2_kernel<<<(BB * TT) / 256, 256, 0, stream>>>(
      useq, x0, (const float*)d_in[14], (const float*)d_in[15],
      (const float*)d_in[16], (const float*)d_in[17], out);
}

// Round 5
// 474.872 us; speedup vs baseline: 1.2952x; 1.2952x over previous
//
#include <hip/hip_runtime.h>

#define TT 1024
#define BB 2048
#define K1 8
#define L2E2 2.8853900817779268f  // 2*log2(e)

// DPP helpers ----------------------------------------------------------------
template <int CTRL>
__device__ __forceinline__ float dpp_add(float x) {
  int y = __builtin_amdgcn_update_dpp(0, __float_as_int(x), CTRL, 0xF, 0xF, true);
  return x + __int_as_float(y);
}
// Sum within each aligned 16-lane row; result replicated in all 16 lanes.
__device__ __forceinline__ float sum16(float x) {
  x = dpp_add<0xB1>(x);   // quad_perm xor1
  x = dpp_add<0x4E>(x);   // quad_perm xor2
  x = dpp_add<0x141>(x);  // row_half_mirror
  x = dpp_add<0x140>(x);  // row_mirror
  return x;
}
__device__ __forceinline__ float rdlane(float x, int l) {
  return __int_as_float(__builtin_amdgcn_readlane(__float_as_int(x), l));
}

// ---------------------------------------------------------------------------
// Phase 1: sequential RK4 scan. ONE element per 64-lane wave:
//   row0 = NN1 / state A,  row1 = NN2 / B,  row2 = NN3 / C,  row3 = dummy.
// Per stage: ONE eval stream (2 transcendentals), ONE sum16 (per-row sums),
// P1/P2/P3 extracted as wave-uniform SGPRs via v_readlane (lanes 0/16/32).
// Every lane: K = fma(-0.1,S,cstS) + a1*P1 + a2*P2 + a3*P3  (per-lane a's).
//   row0: KA = -0.1A + (0.2-C1) + 0.1u          - P1
//   row1: KB = -0.1B + cbC + (5/3)P1 - 3P2 + P3
//   row2: KC = -0.1C + ccC +          P2 - P3
// 2048 waves = 2 waves/SIMD on all 1024 SIMDs; no DS ops; u via scalar loads;
// outputs staged in regs, stores batched per 8-step chunk.
__global__ __launch_bounds__(256) void phase1_kernel(
    const float* __restrict__ useq, const float* __restrict__ x0,
    const float* __restrict__ r1W0, const float* __restrict__ r1b0,
    const float* __restrict__ r1W1, const float* __restrict__ r1b1,
    const float* __restrict__ r2W0, const float* __restrict__ r2b0,
    const float* __restrict__ r2W1, const float* __restrict__ r2b1,
    const float* __restrict__ r3W0, const float* __restrict__ r3b0,
    const float* __restrict__ r3W1, const float* __restrict__ r3b1,
    float* __restrict__ out) {
  const int lane = threadIdx.x & 63;
  const int row = lane >> 4;
  const int j = lane & 15;
  // Element id = global wave id; explicitly wave-uniform (SGPR) so that u
  // loads scalarize to s_load.
  const int e =
      __builtin_amdgcn_readfirstlane(blockIdx.x * 4 + (threadIdx.x >> 6));

  const float* W0p = (row == 0) ? r1W0 : (row == 1) ? r2W0 : r3W0;
  const float* b0p = (row == 0) ? r1b0 : (row == 1) ? r2b0 : r3b0;
  const float* W1p = (row == 0) ? r1W1 : (row == 1) ? r2W1 : r3W1;

  const float w0s = W0p[j] * L2E2;
  const float b0s = b0p[j] * L2E2;
  const float wn = -2.0f * W1p[j];

  // C_i = b1_i + sum_j W1_i[j]  (uniform, init-only).
  float C1 = r1b1[0], C2 = r2b1[0], C3 = r3b1[0];
  for (int q = 0; q < 16; ++q) {
    C1 += r1W1[q];
    C2 += r2W1[q];
    C3 += r3W1[q];
  }
  const float caC = 0.2f - C1;
  const float cbC = -1.0f / 6.0f + (5.0f / 3.0f) * C1 - 3.0f * C2 + C3;
  const float ccC = -1.0f / 6.0f + C2 - C3;

  // Per-lane combine coefficients / constants.
  const float cstBase = (row == 0) ? caC : (row == 1) ? cbC : ccC;
  const float uco = (row == 0) ? 0.1f : 0.0f;
  const float a1 = (row == 0) ? -1.0f : (row == 1) ? (5.0f / 3.0f) : 0.0f;
  const float a2 = (row == 1) ? -3.0f : (row == 2) ? 1.0f : 0.0f;
  const float a3 = (row == 1) ? 1.0f : (row == 2) ? -1.0f : 0.0f;

  float S = x0[e * 15 + ((row < 3) ? row : 2)];

  const float* up = useq + e * TT;          // SGPR base -> scalar loads
  float* op = out + (size_t)e * TT * 4;

#define STAGE(SS, KK)                                                     \
  {                                                                       \
    float rv = __builtin_amdgcn_rcpf(                                     \
        __builtin_amdgcn_exp2f(fmaf(w0s, (SS), b0s)) + 1.0f);             \
    float q = sum16(wn * rv);                                             \
    float P1 = rdlane(q, 0);                                              \
    float P2 = rdlane(q, 16);                                             \
    float P3 = rdlane(q, 32);                                             \
    float t_ = fmaf(-0.1f, (SS), cstS);                                   \
    t_ = fmaf(a1, P1, t_);                                                \
    t_ = fmaf(a2, P2, t_);                                                \
    KK = fmaf(a3, P3, t_);                                                \
  }

#define STEP(UQ, SC_)                                                     \
  {                                                                       \
    const float cstS = fmaf(uco, (UQ), cstBase);                          \
    SC_ = S;                                                              \
    float k1, k2, k3, k4;                                                 \
    STAGE(S, k1)                                                          \
    float s2 = fmaf(0.5f, k1, S);                                         \
    STAGE(s2, k2)                                                         \
    float s3 = fmaf(0.5f, k2, S);                                         \
    STAGE(s3, k3)                                                         \
    float s4 = S + k3;                                                    \
    STAGE(s4, k4)                                                         \
    S = fmaf(1.0f / 6.0f, fmaf(2.0f, k2 + k3, k1) + k4, S);               \
  }

  float uc0, uc1, uc2, uc3, uc4, uc5, uc6, uc7;
  {
    float4 a = *(const float4*)(up);
    float4 b = *(const float4*)(up + 4);
    uc0 = a.x; uc1 = a.y; uc2 = a.z; uc3 = a.w;
    uc4 = b.x; uc5 = b.y; uc6 = b.z; uc7 = b.w;
  }

  for (int t0 = 0; t0 < TT; t0 += K1) {
    const int tn = (t0 + K1 <= TT - K1) ? (t0 + K1) : (TT - K1);
    const float4 na = *(const float4*)(up + tn);
    const float4 nb = *(const float4*)(up + tn + 4);

    float sc0, sc1, sc2, sc3, sc4, sc5, sc6, sc7;
    STEP(uc0, sc0)
    STEP(uc1, sc1)
    STEP(uc2, sc2)
    STEP(uc3, sc3)
    STEP(uc4, sc4)
    STEP(uc5, sc5)
    STEP(uc6, sc6)
    STEP(uc7, sc7)

    // Batched stores: lanes 0/16/32 write components 0/1/2 for 8 steps.
    if (j == 0 && row < 3) {
      float* p = op + t0 * 4 + row;
      p[0] = sc0;  p[4] = sc1;  p[8] = sc2;  p[12] = sc3;
      p[16] = sc4; p[20] = sc5; p[24] = sc6; p[28] = sc7;
    }

    uc0 = na.x; uc1 = na.y; uc2 = na.z; uc3 = na.w;
    uc4 = nb.x; uc5 = nb.y; uc6 = nb.z; uc7 = nb.w;
  }
#undef STEP
#undef STAGE
}

// ---------------------------------------------------------------------------
// Phase 2: out[b,t,3] = estC(z_t). One block per batch row; each thread
// handles 4 samples (t = k*256 + tid) so the 128 LDS weight-reads per h-loop
// are amortized 4x. All z-loads issued before the fma loop (latency overlap).
__global__ __launch_bounds__(256) void phase2_kernel(
    const float* __restrict__ useq, const float* __restrict__ x0,
    const float* __restrict__ W0, const float* __restrict__ b0,
    const float* __restrict__ W1, const float* __restrict__ b1p,
    float* __restrict__ out) {
  __shared__ float4 wrow[32][4];  // {w0..3},{w4..7},{w8..11},{b0s,w1n,-,-}
  for (int idx = threadIdx.x; idx < 512; idx += 256) {
    const int h = idx >> 4, r = idx & 15;
    float v = 0.0f;
    if (r < 12) v = W0[r * 32 + h] * L2E2;
    else if (r == 12) v = b0[h] * L2E2;
    else if (r == 13) v = -2.0f * W1[h];
    ((float*)&wrow[h][0])[r] = v;
  }
  __syncthreads();

  float base = b1p[0];
#pragma unroll
  for (int h = 0; h < 32; ++h) base += W1[h];  // uniform s_loads, cached

  const int b = blockIdx.x;
  const float* xrow = x0 + b * 15;

  float z[4][12];
#pragma unroll
  for (int k = 0; k < 4; ++k) {
    const int t = k * 256 + (int)threadIdx.x;
    const int g = (b << 10) + t;
    if (t >= 4) {
      const float* px = out + (size_t)g * 4;
#pragma unroll
      for (int i = 0; i < 4; ++i) {
        z[k][2 * i] = px[(i - 4) * 4 + 0];
        z[k][2 * i + 1] = px[(i - 4) * 4 + 1];
      }
      const float* pu = useq + g;
#pragma unroll
      for (int i = 0; i < 4; ++i) z[k][8 + i] = pu[i - 4];
    } else {
#pragma unroll
      for (int i = 0; i < 4; ++i) {
        const int s4 = t - 4 + i;
        const float* py = (s4 >= 0) ? (out + ((size_t)(b << 10) + s4) * 4)
                                    : (xrow + 3 + 2 * (i + t));
        z[k][2 * i] = py[0];
        z[k][2 * i + 1] = py[1];
        const float* pu = (s4 >= 0) ? (useq + (b << 10) + s4)
                                    : (xrow + 11 + i + t);
        z[k][8 + i] = pu[0];
      }
    }
  }

  float ov0 = base, ov1 = base, ov2 = base, ov3 = base;
#pragma unroll
  for (int h = 0; h < 32; ++h) {
    const float4 wa = wrow[h][0];
    const float4 wb = wrow[h][1];
    const float4 wc = wrow[h][2];
    const float4 wd = wrow[h][3];
#define ACC(OV, ZZ)                                                       \
  {                                                                       \
    float a = wd.x;                                                       \
    a = fmaf(ZZ[0], wa.x, a);  a = fmaf(ZZ[1], wa.y, a);                  \
    a = fmaf(ZZ[2], wa.z, a);  a = fmaf(ZZ[3], wa.w, a);                  \
    a = fmaf(ZZ[4], wb.x, a);  a = fmaf(ZZ[5], wb.y, a);                  \
    a = fmaf(ZZ[6], wb.z, a);  a = fmaf(ZZ[7], wb.w, a);                  \
    a = fmaf(ZZ[8], wc.x, a);  a = fmaf(ZZ[9], wc.y, a);                  \
    a = fmaf(ZZ[10], wc.z, a); a = fmaf(ZZ[11], wc.w, a);                 \
    const float r = __builtin_amdgcn_rcpf(__builtin_amdgcn_exp2f(a) + 1.0f); \
    OV = fmaf(wd.y, r, OV);                                               \
  }
    ACC(ov0, z[0])
    ACC(ov1, z[1])
    ACC(ov2, z[2])
    ACC(ov3, z[3])
#undef ACC
  }

  const size_t gb = (size_t)(b << 10) + threadIdx.x;
  out[(gb + 0) * 4 + 3] = ov0;
  out[(gb + 256) * 4 + 3] = ov1;
  out[(gb + 512) * 4 + 3] = ov2;
  out[(gb + 768) * 4 + 3] = ov3;
}

// ---------------------------------------------------------------------------
extern "C" void kernel_launch(void* const* d_in, const int* in_sizes, int n_in,
                              void* d_out, int out_size, void* d_ws,
                              size_t ws_size, hipStream_t stream) {
  const float* useq = (const float*)d_in[0];
  const float* x0 = (const float*)d_in[1];
  float* out = (float*)d_out;

  phase1_kernel<<<BB / 4, 256, 0, stream>>>(
      useq, x0,
      (const float*)d_in[2], (const float*)d_in[3], (const float*)d_in[4],
      (const float*)d_in[5], (const float*)d_in[6], (const float*)d_in[7],
      (const float*)d_in[8], (const float*)d_in[9], (const float*)d_in[10],
      (const float*)d_in[11], (const float*)d_in[12], (const float*)d_in[13],
      out);

  phase2_kernel<<<BB, 256, 0, stream>>>(
      useq, x0, (const float*)d_in[14], (const float*)d_in[15],
      (const float*)d_in[16], (const float*)d_in[17], out);
}